// Round 14
// baseline (408.860 us; speedup 1.0000x reference)
//
#include <hip/hip_runtime.h>
#include <hip/hip_bf16.h>
#include <math.h>

typedef __hip_bfloat16 bf16;
typedef unsigned long long u64;
typedef unsigned int u32;

#define LTT 4
#define DIM 256
#define NTOK 32768      // total tokens (4*8*1024)
#define MT 2097152      // elements per time step (8192 tokens * 256)
#define NTOT 8388608

typedef __attribute__((ext_vector_type(8))) short short8;   // 8 bf16 (4 VGPRs)
typedef __attribute__((ext_vector_type(4))) float f32x4;
typedef __attribute__((ext_vector_type(4))) u32 u32x4;

// dual-dtype load with finite clamp: f=1 -> fp32, f=0 -> bf16
__device__ __forceinline__ float ldin(const void* p, size_t i, int f) {
  float v = f ? ((const float*)p)[i] : __bfloat162float(((const bf16*)p)[i]);
  return isfinite(v) ? v : 0.0f;
}

__device__ __forceinline__ short bf16bits(float x) {
  union { bf16 b; short s; } u; u.b = __float2bfloat16(x); return u.s;
}

// ---------------- per-input dtype probes, all inputs in one launch ----------------
struct PtrPack { const void* p[14]; int n[14]; };

__global__ void probe_all_k(PtrPack pk, int* flags) {
  int b = blockIdx.x;            // 14 blocks, one per input
  int tid = threadIdx.x;         // 64
  const unsigned short* u = (const unsigned short*)pk.p[b];
  int nelem = pk.n[b];
  int n = nelem < 1024 ? nelem : 1024;
  bool big = false, nz = false;
  for (int i = tid; i < n; i += 64) {
    unsigned short h = u[i];
    if (((h >> 7) & 0xFF) >= 0xC0) big = true;
    if (h != 0) nz = true;
  }
  u64 bm = __ballot(big);
  u64 zm = __ballot(nz);
  if (tid == 0) {
    unsigned short h0 = u[0];
    int f = 0;
    if (bm != 0ull) f = 1;
    else if (h0 == 0 && (zm != 0ull || n == 1)) f = 1;
    flags[b] = f;
    if (b == 0) flags[15] = 1;   // const fp32 flag
  }
}

// ---------------- batchnorm stats (BN1 only; BN2 fused into Wo epilogue) ----------
__global__ void __launch_bounds__(1024)
bnstats_k(const void* __restrict__ x, const int* __restrict__ fxp,
          float* __restrict__ gsum, float* __restrict__ gsq) {
  int fx = *fxp;
  int c = threadIdx.x & 255;            // channel
  int part = threadIdx.x >> 8;          // 0..3
  int tok0 = blockIdx.x * 128 + part * 32;
  float s = 0.f, q = 0.f;
  for (int t = 0; t < 32; t++) {
    float v = ldin(x, (size_t)(tok0 + t) * DIM + c, fx);
    s += v; q += v * v;
  }
  __shared__ float ls[4][256], lq[4][256];
  ls[part][c] = s; lq[part][c] = q;
  __syncthreads();
  if (threadIdx.x < 256) {
    float S = ls[0][c] + ls[1][c] + ls[2][c] + ls[3][c];
    float Q = lq[0][c] + lq[1][c] + lq[2][c] + lq[3][c];
    atomicAdd(&gsum[c], S);
    atomicAdd(&gsq[c], Q);
  }
}

// Morton interleave: bit j of x -> bit 2j; used to pack paired spike ballots.
__device__ __forceinline__ u64 mort(u32 x) {
  u64 v = x;
  v = (v | (v << 16)) & 0x0000FFFF0000FFFFull;
  v = (v | (v << 8))  & 0x00FF00FF00FF00FFull;
  v = (v | (v << 4))  & 0x0F0F0F0F0F0F0F0Full;
  v = (v | (v << 2))  & 0x3333333333333333ull;
  v = (v | (v << 1))  & 0x5555555555555555ull;
  return v;
}

// ---------------- fused BN-apply + LIF scan; 2 elements/thread, vector loads ------
__global__ void lif_k(const void* __restrict__ x, const int* __restrict__ fxp,
                      const float* __restrict__ gsum, const float* __restrict__ gsq,
                      const void* __restrict__ gamma, const int* __restrict__ fgp,
                      const void* __restrict__ beta, const int* __restrict__ fbp,
                      u64* __restrict__ bits) {
  int fx = *fxp, fg = *fgp, fb = *fbp;
  int m2 = (blockIdx.x * 256 + threadIdx.x) * 2;   // even element index in [0, MT)
  int c0 = m2 & (DIM - 1), c1 = c0 + 1;
  int lane = threadIdx.x & 63;
  float mean0 = gsum[c0] * (1.0f / 32768.0f), mean1 = gsum[c1] * (1.0f / 32768.0f);
  float var0 = gsq[c0] * (1.0f / 32768.0f) - mean0 * mean0;
  float var1 = gsq[c1] * (1.0f / 32768.0f) - mean1 * mean1;
  float inv0 = rsqrtf(var0 + 1e-5f), inv1 = rsqrtf(var1 + 1e-5f);
  float g0 = ldin(gamma, c0, fg), g1 = ldin(gamma, c1, fg);
  float be0 = ldin(beta, c0, fb), be1 = ldin(beta, c1, fb);
  float xn0[LTT], xn1[LTT];
  #pragma unroll
  for (int t = 0; t < LTT; t++) {
    size_t e = (size_t)t * MT + m2;
    float v0, v1;
    if (fx) {
      float2 p2 = *(const float2*)((const float*)x + e);
      v0 = p2.x; v1 = p2.y;
    } else {
      u32 pw = *(const u32*)((const unsigned short*)x + e);
      v0 = __uint_as_float((pw & 0xFFFFu) << 16);
      v1 = __uint_as_float(pw & 0xFFFF0000u);
    }
    if (!isfinite(v0)) v0 = 0.f;
    if (!isfinite(v1)) v1 = 0.f;
    xn0[t] = (v0 - mean0) * inv0 * g0 + be0;
    xn1[t] = (v1 - mean1) * inv1 * g1 + be1;
  }
  float va = 0.f, vb = 0.f;
  #pragma unroll
  for (int t = 0; t < LTT; t++) {
    va = va + (xn0[t] - va) * 0.5f;          // TAU = 2
    vb = vb + (xn1[t] - vb) * 0.5f;
    bool sp0 = (va - 1.0f >= 0.0f);          // VTH = 1
    bool sp1 = (vb - 1.0f >= 0.0f);
    u64 b0 = __ballot(sp0);
    u64 b1 = __ballot(sp1);
    if (lane == 0) {
      size_t ebase = (size_t)t * MT + (size_t)(blockIdx.x * 256 + (threadIdx.x & ~63)) * 2;
      bits[(ebase >> 6)]     = mort((u32)b0)         | (mort((u32)b1) << 1);
      bits[(ebase >> 6) + 1] = mort((u32)(b0 >> 32)) | (mort((u32)(b1 >> 32)) << 1);
    }
    va = sp0 ? 0.0f : va;
    vb = sp1 ? 0.0f : vb;
  }
}

// fast erf: Abramowitz-Stegun 7.1.26, |err| <= 1.5e-7 (4 orders below bf16-h quant)
__device__ __forceinline__ float erf_fast(float x) {
  float ax = fabsf(x);
  float t = 1.0f / fmaf(0.3275911f, ax, 1.0f);
  float p = t * fmaf(t, fmaf(t, fmaf(t, fmaf(t, 1.061405429f, -1.453152027f),
                                     1.421413741f), -0.284496736f), 0.254829592f);
  float r = 1.0f - p * __expf(-ax * ax);
  return copysignf(r, x);
}

__device__ __forceinline__ float gelu_f(float x) {
  return 0.5f * x * (1.0f + erf_fast(x * 0.70710678118654752440f));
}

// ---------------- one-time weight convert+transpose (all 4 weights, one launch) ----
__global__ void wconv_all_k(const void* __restrict__ Wqkv, const void* __restrict__ Wo,
                            const void* __restrict__ W1, const void* __restrict__ W2,
                            const int* __restrict__ flags,
                            bf16* __restrict__ wqkvt, bf16* __restrict__ wot,
                            bf16* __restrict__ w1t, bf16* __restrict__ w2t) {
  int b = blockIdx.x, t = threadIdx.x;
  const void* W; const int* f; bf16* o; int K, N, n, kblk = 0;
  if (b < 768)       { W = Wqkv; f = flags + 3;  o = wqkvt; K = 256;  N = 768;  n = b; }
  else if (b < 1024) { W = Wo;   f = flags + 5;  o = wot;   K = 256;  N = 256;  n = b - 768; }
  else if (b < 2048) { W = W1;   f = flags + 9;  o = w1t;   K = 256;  N = 1024; n = b - 1024; }
  else { W = W2; f = flags + 11; o = w2t; K = 1024; N = 256;
         int q = b - 2048; kblk = q >> 8; n = q & 255; }
  int k = kblk * 256 + t;
  o[(size_t)n * K + k] = __float2bfloat16(ldin(W, (size_t)k * N + n, *f));
}

// ---------------- LDS-free direct MFMA GEMM, 128x128 tile, 4 waves ----------------
// MODE 3: O(bf16) = acc+bias    (qkv spike GEMM)
// MODE 4: Of32 = xin + scl*(acc+bias)
// MODE 5: MODE 4 + fused per-channel BN stats (Sum, SumSq) -> gs2/gq2
template <int MODE, int ABITS>
__global__ void __launch_bounds__(256)
dgemm_k(const void* __restrict__ Av, const bf16* __restrict__ Bt,
        const void* __restrict__ biasv, const int* __restrict__ fbp,
        void* O, const void* xinv, const int* __restrict__ fxp,
        const void* __restrict__ scalev, const int* __restrict__ fsp,
        int N, int K, size_t obase,
        float* __restrict__ gs2, float* __restrict__ gq2) {
  int tid = threadIdx.x;
  int lane = tid & 63, w = tid >> 6;
  int wr = w >> 1, wc = w & 1;          // wave -> 64x64 quadrant
  int kq = lane >> 4, lr = lane & 15;
  int bm = blockIdx.y * 128, bn = blockIdx.x * 128;
  f32x4 acc[4][4] = {};
  __shared__ float lsum[128], lsq[128];
  if constexpr (MODE == 5) {
    if (tid < 128) { lsum[tid] = 0.f; lsq[tid] = 0.f; }
    __syncthreads();
  }

  if constexpr (ABITS) {
    // K = 256 fixed for spike GEMMs.
    __shared__ __align__(16) short lut[256][8];
    {
      short8 e;
      #pragma unroll
      for (int j = 0; j < 8; j++) e[j] = ((tid >> j) & 1) ? (short)0x3F80 : (short)0;
      *(short8*)&lut[tid][0] = e;
    }
    const u32* Abits = (const u32*)Av;
    u32 ab[4][8];
    #pragma unroll
    for (int i = 0; i < 4; i++) {
      const u32* rp = &Abits[(size_t)(bm + wr * 64 + i * 16 + lr) * 8];
      *(u32x4*)&ab[i][0] = *(const u32x4*)&rp[0];
      *(u32x4*)&ab[i][4] = *(const u32x4*)&rp[4];
    }
    __syncthreads();
    #pragma unroll
    for (int s = 0; s < 8; s++) {        // k0 = s*32
      short8 af[4], bf[4];
      #pragma unroll
      for (int i = 0; i < 4; i++) {
        u32 byte = (ab[i][s] >> (kq * 8)) & 0xFFu;
        af[i] = *(const short8*)&lut[byte][0];
      }
      #pragma unroll
      for (int j = 0; j < 4; j++)
        bf[j] = *(const short8*)&Bt[(size_t)(bn + wc * 64 + j * 16 + lr) * 256 + s * 32 + kq * 8];
      __builtin_amdgcn_s_setprio(1);
      #pragma unroll
      for (int i = 0; i < 4; i++)
        #pragma unroll
        for (int j = 0; j < 4; j++)
          acc[i][j] = __builtin_amdgcn_mfma_f32_16x16x32_bf16(af[i], bf[j], acc[i][j], 0, 0, 0);
      __builtin_amdgcn_s_setprio(0);
    }
  } else {
    const bf16* Ab = (const bf16*)Av;
    for (int k0 = 0; k0 < K; k0 += 32) {
      short8 af[4], bf[4];
      #pragma unroll
      for (int i = 0; i < 4; i++)
        af[i] = *(const short8*)&Ab[(size_t)(bm + wr * 64 + i * 16 + lr) * K + k0 + kq * 8];
      #pragma unroll
      for (int j = 0; j < 4; j++)
        bf[j] = *(const short8*)&Bt[(size_t)(bn + wc * 64 + j * 16 + lr) * K + k0 + kq * 8];
      __builtin_amdgcn_s_setprio(1);
      #pragma unroll
      for (int i = 0; i < 4; i++)
        #pragma unroll
        for (int j = 0; j < 4; j++)
          acc[i][j] = __builtin_amdgcn_mfma_f32_16x16x32_bf16(af[i], bf[j], acc[i][j], 0, 0, 0);
      __builtin_amdgcn_s_setprio(0);
    }
  }

  // epilogue: D layout col=lane&15, row=(lane>>4)*4+r (verified mapping)
  float scl = 0.f;
  int fx = 0, fbias = *fbp;
  if (MODE >= 4) { scl = ldin(scalev, 0, *fsp); fx = *fxp; }
  int row0 = bm + wr * 64 + kq * 4;
  int col0 = bn + wc * 64 + lr;
  #pragma unroll
  for (int j = 0; j < 4; j++) {
    int n = col0 + j * 16;
    float bb = ldin(biasv, n, fbias);
    float sj = 0.f, qj = 0.f;
    #pragma unroll
    for (int i = 0; i < 4; i++) {
      #pragma unroll
      for (int r = 0; r < 4; r++) {
        int m = row0 + i * 16 + r;
        float v = acc[i][j][r] + bb;
        size_t o = obase + (size_t)m * N + n;
        if (MODE == 3) {
          ((bf16*)O)[o] = __float2bfloat16(v);
        } else {  // MODE 4/5: fp32 RMW; same element same thread
          float basev = ldin(xinv, o, fx);
          float ov = basev + scl * v;
          ((float*)O)[o] = ov;
          sj += ov; qj += ov * ov;
        }
      }
    }
    if constexpr (MODE == 5) {
      int li = wc * 64 + j * 16 + lr;
      atomicAdd(&lsum[li], sj);
      atomicAdd(&lsq[li], qj);
    }
  }
  if constexpr (MODE == 5) {
    __syncthreads();
    if (tid < 128) {
      atomicAdd(&gs2[bn + tid], lsum[tid]);
      atomicAdd(&gq2[bn + tid], lsq[tid]);
    }
  }
}

// ---------------- fused FFN v4 + T5 setprio around MFMA clusters ------------------
// out += scl*(gelu(spikes@W1+b1)@W2+b2), 512 blocks x 64 tokens x 8 waves.
// LDS = lut 4K + As 32K + hl-dbuf 32K = 68 KB, 2 blocks/CU at different phases ->
// setprio has role diversity to arbitrate (T5 regime). One barrier per chunk.
// NOTE (R10): W1 next-chunk register preload REGRESSED; do not re-add.
__global__ void __launch_bounds__(512)
ffn_k(const u64* __restrict__ bits_, const bf16* __restrict__ w1t,
      const void* __restrict__ b1v, const int* __restrict__ f1p,
      const bf16* __restrict__ w2t,
      const void* __restrict__ b2v, const int* __restrict__ f2p,
      float* out, const void* __restrict__ scalev, const int* __restrict__ fsp) {
  __shared__ __align__(16) short lut[256][8];       // 4 KB byte->8xbf16
  __shared__ __align__(16) short As[32][64][8];     // 32 KB expanded spikes [kb][row]
  __shared__ __align__(16) short hl[2][16][64][8];  // 32 KB h chunk dbuf, kb-major
  int tid = threadIdx.x;            // 512
  int lane = tid & 63, w = tid >> 6;   // 8 waves
  int kq = lane >> 4, lr = lane & 15;
  int m0 = blockIdx.x * 64;
  if (tid < 256) {
    short8 e;
    #pragma unroll
    for (int j = 0; j < 8; j++) e[j] = ((tid >> j) & 1) ? (short)0x3F80 : (short)0;
    *(short8*)&lut[tid][0] = e;
  }
  __syncthreads();
  // ---- expand spikes once: thread t -> row t>>3, u32 word t&7 (kb = 4*(t&7)..+3)
  {
    int row = tid >> 3, word = tid & 7;
    u32 val = ((const u32*)bits_)[(size_t)(m0 + row) * 8 + word];
    #pragma unroll
    for (int q = 0; q < 4; q++) {
      u32 byte = (val >> (q * 8)) & 0xFFu;
      *(short8*)&As[word * 4 + q][row][0] = *(const short8*)&lut[byte][0];
    }
  }
  int f1 = *f1p;
  f32x4 acc2[4][2] = {};
  __syncthreads();

  for (int c = 0; c < 8; c++) {
    // ---- phase A: wave w -> hidden cols c*128 + w*16 .. +15
    f32x4 accA[4] = {};
    #pragma unroll
    for (int s = 0; s < 8; s++) {
      short8 bfw = *(const short8*)&w1t[(size_t)(c * 128 + w * 16 + lr) * 256 + s * 32 + kq * 8];
      __builtin_amdgcn_s_setprio(1);
      #pragma unroll
      for (int i = 0; i < 4; i++) {
        short8 af = *(const short8*)&As[s * 4 + kq][i * 16 + lr][0];
        accA[i] = __builtin_amdgcn_mfma_f32_16x16x32_bf16(af, bfw, accA[i], 0, 0, 0);
      }
      __builtin_amdgcn_s_setprio(0);
    }
    // gelu + bf16 -> hl[c&1][cl>>3][row][cl&7]
    {
      int cl = w * 16 + lr;
      float bb = ldin(b1v, c * 128 + cl, f1);
      #pragma unroll
      for (int i = 0; i < 4; i++)
        #pragma unroll
        for (int r = 0; r < 4; r++)
          hl[c & 1][cl >> 3][i * 16 + kq * 4 + r][cl & 7] = bf16bits(gelu_f(accA[i][r] + bb));
    }
    // preload W2 fragments for phase B (hides L2 latency under the barrier)
    short8 pb[4][2];
    #pragma unroll
    for (int ks = 0; ks < 4; ks++) {
      pb[ks][0] = *(const short8*)&w2t[(size_t)(w * 32 + lr) * 1024 + c * 128 + ks * 32 + kq * 8];
      pb[ks][1] = *(const short8*)&w2t[(size_t)(w * 32 + 16 + lr) * 1024 + c * 128 + ks * 32 + kq * 8];
    }
    __syncthreads();
    // ---- phase B: wave w -> out cols w*32 .. +31
    __builtin_amdgcn_s_setprio(1);
    #pragma unroll
    for (int ks = 0; ks < 4; ks++) {
      #pragma unroll
      for (int i = 0; i < 4; i++) {
        short8 af = *(const short8*)&hl[c & 1][ks * 4 + kq][i * 16 + lr][0];
        acc2[i][0] = __builtin_amdgcn_mfma_f32_16x16x32_bf16(af, pb[ks][0], acc2[i][0], 0, 0, 0);
        acc2[i][1] = __builtin_amdgcn_mfma_f32_16x16x32_bf16(af, pb[ks][1], acc2[i][1], 0, 0, 0);
      }
    }
    __builtin_amdgcn_s_setprio(0);
  }

  float scl = ldin(scalev, 0, *fsp);
  int f2 = *f2p;
  #pragma unroll
  for (int j = 0; j < 2; j++) {
    int n = w * 32 + j * 16 + lr;
    float bb = ldin(b2v, n, f2);
    #pragma unroll
    for (int i = 0; i < 4; i++)
      #pragma unroll
      for (int r = 0; r < 4; r++) {
        int row = m0 + i * 16 + kq * 4 + r;
        size_t o = (size_t)row * 256 + n;
        out[o] = out[o] + scl * (acc2[i][j][r] + bb);  // same-thread read-then-write
      }
  }
}

// ---------------- region-mean of spike bits: sreg[512][256] fp32 ----------------
__global__ void regmean_k(const u64* __restrict__ bits, float* __restrict__ sreg) {
  int blk = blockIdx.x;   // 512 regions
  int c = threadIdx.x;    // 256
  float s = 0.f;
  for (int i = 0; i < 64; i++) {
    u64 w = bits[(size_t)(blk * 64 + i) * 4 + (c >> 6)];
    s += (float)((w >> (c & 63)) & 1ull);
  }
  sreg[(size_t)blk * 256 + c] = s * (1.0f / 64.0f);
}

// ---------------- routing projection: qkr[512][512] = sreg @ Wqkv[:, :512] + bqkv ----
__global__ void __launch_bounds__(256)
pgemm_k(const float* __restrict__ A,          // sreg [512][256]
        const void* __restrict__ Bv, const int* __restrict__ fBp,   // Wqkv, row stride 768
        const void* __restrict__ biasv, const int* __restrict__ fbp,
        float* __restrict__ Oq) {             // qkr [512][512]
  int fB = *fBp, fb = *fbp;
  __shared__ float Ast[16][68];
  __shared__ float Bs[16][68];
  int tid = threadIdx.x;
  int bm = blockIdx.y * 64, bn = blockIdx.x * 64;
  int tr = tid >> 4, tc = tid & 15;
  float acc[4][4] = {};
  for (int k0 = 0; k0 < 256; k0 += 16) {
    for (int t = tid; t < 1024; t += 256) {
      int m = t >> 4, k = t & 15;
      Ast[k][m] = A[(size_t)(bm + m) * 256 + k0 + k];
    }
    for (int t = tid; t < 1024; t += 256) {
      int k = t >> 6, n = t & 63;
      Bs[k][n] = ldin(Bv, (size_t)(k0 + k) * 768 + bn + n, fB);
    }
    __syncthreads();
    #pragma unroll
    for (int kk = 0; kk < 16; kk++) {
      float4 a4 = *(const float4*)&Ast[kk][tr * 4];
      float4 b4 = *(const float4*)&Bs[kk][tc * 4];
      float a[4] = {a4.x, a4.y, a4.z, a4.w};
      float b[4] = {b4.x, b4.y, b4.z, b4.w};
      #pragma unroll
      for (int i = 0; i < 4; i++)
        #pragma unroll
        for (int jj = 0; jj < 4; jj++)
          acc[i][jj] += a[i] * b[jj];
    }
    __syncthreads();
  }
  #pragma unroll
  for (int i = 0; i < 4; i++)
    #pragma unroll
    for (int jj = 0; jj < 4; jj++) {
      int n = bn + tc * 4 + jj;
      Oq[(size_t)(bm + tr * 4 + i) * 512 + n] = acc[i][jj] + ldin(biasv, n, fb);
    }
}

// ---------------- affinity + top-4 (ties -> lowest index, matches lax.top_k) ----------------
__global__ void afftopk_k(const float* __restrict__ qkr, int* __restrict__ idx) {
  int blk = blockIdx.x;       // (t*8+b)*16 + r
  int tb = blk >> 4;
  int tid = threadIdx.x;      // 256
  int s_ = tid >> 4, p = tid & 15;
  __shared__ float part[256];
  __shared__ float aff[16];
  const float* qrow = qkr + (size_t)blk * 512;                 // q half
  const float* krow = qkr + (size_t)(tb * 16 + s_) * 512 + 256; // k half
  float acc = 0.f;
  for (int c = p * 16; c < p * 16 + 16; c++) acc += qrow[c] * krow[c];
  part[tid] = acc;
  __syncthreads();
  if (tid < 16) {
    float a = 0.f;
    for (int pp = 0; pp < 16; pp++) a += part[tid * 16 + pp];
    aff[tid] = a;
  }
  __syncthreads();
  if (tid == 0) {
    bool taken[16] = {};
    for (int kk = 0; kk < 4; kk++) {
      float best = -INFINITY; int bi = 0;
      for (int i = 0; i < 16; i++)
        if (!taken[i] && aff[i] > best) { best = aff[i]; bi = i; }
      taken[bi] = true;
      idx[blk * 4 + kk] = bi;
    }
  }
}

// ---------------- MFMA gathered attention per (b_local, r, h) ----------------
// 48 KB LDS (3 blocks/CU): Ks region is dead after QK^T, so Ps for waves 2,3
// overlay it. T5 setprio around QK^T and PV MFMA clusters (3 blocks/CU at
// different phases -> role diversity).
__global__ void __launch_bounds__(256)
attn_k(const bf16* __restrict__ qkv, const int* __restrict__ idx,
       bf16* __restrict__ ctx) {
  __shared__ __align__(16) short KP[8192];        // 16 KB: Ks[256][32] -> Ps waves 2,3
  __shared__ __align__(16) short Vs[32][256];     // 16 KB (rotated V^T)
  __shared__ __align__(16) short P01[8192];       // 16 KB: Ps waves 0,1
  int blk = blockIdx.x;             // (b_local*16+r)*8 + h
  int h = blk & 7, br = blk >> 3;
  int b = br >> 4;                  // chunk-local batch
  int tid = threadIdx.x;
  int base = br * 64;               // chunk-local token base
  int r0 = idx[br * 4 + 0], r1 = idx[br * 4 + 1];
  int r2 = idx[br * 4 + 2], r3 = idx[br * 4 + 3];

  #pragma unroll
  for (int c = 0; c < 4; c++) {
    int g = c * 256 + tid;
    int tk = g >> 2, ch = g & 3;
    int rs = tk >> 6;
    int rid = (rs & 2) ? ((rs & 1) ? r3 : r2) : ((rs & 1) ? r1 : r0);
    int gt = b * 1024 + rid * 64 + (tk & 63);
    short8 v = *(const short8*)&qkv[(size_t)gt * 768 + 256 + h * 32 + ch * 8];
    *(short8*)&KP[tk * 32 + ch * 8] = v;
  }
  {
    int tk = tid;
    int rs = tk >> 6;
    int rid = (rs & 2) ? ((rs & 1) ? r3 : r2) : ((rs & 1) ? r1 : r0);
    int gt = b * 1024 + rid * 64 + (tk & 63);
    const bf16* vp = &qkv[(size_t)gt * 768 + 512 + h * 32];
    short vv[32];
    *(short8*)&vv[0]  = *(const short8*)&vp[0];
    *(short8*)&vv[8]  = *(const short8*)&vp[8];
    *(short8*)&vv[16] = *(const short8*)&vp[16];
    *(short8*)&vv[24] = *(const short8*)&vp[24];
    #pragma unroll
    for (int d = 0; d < 32; d++)
      Vs[d][(tk + 8 * d) & 255] = vv[d];
  }
  __syncthreads();

  int w = tid >> 6, lane = tid & 63, kq = lane >> 4, lr = lane & 15;

  short8 qf = *(const short8*)&qkv[(size_t)(base + w * 16 + lr) * 768 + h * 32 + kq * 8];

  f32x4 s[16];
  __builtin_amdgcn_s_setprio(1);
  #pragma unroll
  for (int nt = 0; nt < 16; nt++) {
    short8 kf = *(const short8*)&KP[(nt * 16 + lr) * 32 + kq * 8];
    f32x4 z = {0.f, 0.f, 0.f, 0.f};
    s[nt] = __builtin_amdgcn_mfma_f32_16x16x32_bf16(qf, kf, z, 0, 0, 0);
  }
  __builtin_amdgcn_s_setprio(0);

  const float cs = 0.17677669529663687f;   // 1/sqrt(32)
  float mx[4] = {-INFINITY, -INFINITY, -INFINITY, -INFINITY};
  #pragma unroll
  for (int nt = 0; nt < 16; nt++)
    #pragma unroll
    for (int r = 0; r < 4; r++) mx[r] = fmaxf(mx[r], s[nt][r]);
  #pragma unroll
  for (int m = 1; m < 16; m <<= 1)
    #pragma unroll
    for (int r = 0; r < 4; r++) mx[r] = fmaxf(mx[r], __shfl_xor(mx[r], m, 64));
  float sum[4] = {0.f, 0.f, 0.f, 0.f};
  #pragma unroll
  for (int nt = 0; nt < 16; nt++)
    #pragma unroll
    for (int r = 0; r < 4; r++) {
      float e = __expf((s[nt][r] - mx[r]) * cs);
      s[nt][r] = e; sum[r] += e;
    }
  #pragma unroll
  for (int m = 1; m < 16; m <<= 1)
    #pragma unroll
    for (int r = 0; r < 4; r++) sum[r] += __shfl_xor(sum[r], m, 64);
  float inv[4];
  #pragma unroll
  for (int r = 0; r < 4; r++) inv[r] = 1.0f / sum[r];

  __syncthreads();   // all waves done reading Ks (KP) before Ps overlays it

  short* Pw = (w < 2) ? &P01[w * 4096] : &KP[(w - 2) * 4096];
  #pragma unroll
  for (int nt = 0; nt < 16; nt++)
    #pragma unroll
    for (int r = 0; r < 4; r++) {
      int row = kq * 4 + r;
      int col = nt * 16 + lr;
      Pw[row * 256 + (col ^ ((row & 7) << 3))] = bf16bits(s[nt][r] * inv[r]);
    }
  __syncthreads();

  f32x4 o0 = {0.f, 0.f, 0.f, 0.f}, o1 = {0.f, 0.f, 0.f, 0.f};
  __builtin_amdgcn_s_setprio(1);
  #pragma unroll
  for (int kc = 0; kc < 8; kc++) {
    short8 pf = *(const short8*)
        &Pw[lr * 256 + (kc ^ ((lr >> 2) & 1)) * 32 + (kq ^ (lr & 3)) * 8];
    int d0 = lr, d1 = 16 + lr;
    short8 vf0 = *(const short8*)&Vs[d0][(kc * 32 + kq * 8 + 8 * d0) & 255];
    short8 vf1 = *(const short8*)&Vs[d1][(kc * 32 + kq * 8 + 8 * d1) & 255];
    o0 = __builtin_amdgcn_mfma_f32_16x16x32_bf16(pf, vf0, o0, 0, 0, 0);
    o1 = __builtin_amdgcn_mfma_f32_16x16x32_bf16(pf, vf1, o1, 0, 0, 0);
  }
  __builtin_amdgcn_s_setprio(0);

  #pragma unroll
  for (int r = 0; r < 4; r++) {
    int q = base + w * 16 + kq * 4 + r;
    ctx[(size_t)q * 256 + h * 32 + lr]      = __float2bfloat16(o0[r]);
    ctx[(size_t)q * 256 + h * 32 + 16 + lr] = __float2bfloat16(o1[r]);
  }
}

// ---------------- launch ----------------
extern "C" void kernel_launch(void* const* d_in, const int* in_sizes, int n_in,
                              void* d_out, int out_size, void* d_ws, size_t ws_size,
                              hipStream_t stream) {
  const void* x_in = d_in[0];
  const void* Wqkv = d_in[3];
  const void* bqkv = d_in[4];
  const void* Wo   = d_in[5];
  const void* bo   = d_in[6];
  const void* W1   = d_in[9];
  const void* b1   = d_in[10];
  const void* W2   = d_in[11];
  const void* b2   = d_in[12];
  const void* scale = d_in[13];

  const size_t MISC = 256 + 1048576 + 524288 + 8192 + 1048576 + 4096
                    + 393216 + 131072 + 524288 + 524288;
  int C;  // batches (of 1024 tokens) per attention chunk; 32 = whole tensor
  if      (MISC + (size_t)32 * 2097152 <= ws_size) C = 32;   // ~68.2 MB
  else if (MISC + (size_t)16 * 2097152 <= ws_size) C = 16;   // ~37.7 MB
  else if (MISC + (size_t)8  * 2097152 <= ws_size) C = 8;    // ~20.9 MB
  else if (MISC + (size_t)4  * 2097152 <= ws_size) C = 4;    // ~12.5 MB
  else                                             C = 1;
  size_t r0 = (size_t)C * 2097152;   // qkvb (C*1.5MB) + ctxb (C*0.5MB)

  char* ws = (char*)d_ws;
  int*  flags = (int*)ws;      // [0..13] per-input dtype; [14]=0 (bf16); [15]=1 (fp32)
  char* p = ws + 256;
  bf16* qkvb = (bf16*)p;
  bf16* ctxb = (bf16*)(p + (size_t)C * 1572864);
  p += r0;
  float* qkr  = (float*)p;  p += 1048576;   // [512][512] (q||k routing projections)
  float* sreg = (float*)p;  p += 524288;    // [512][256] region means
  int*   idxb = (int*)p;    p += 8192;
  u64*   bits = (u64*)p;    p += 1048576;   // s1 bits, later s2 bits
  float* gsum = (float*)p;  p += 4096;      // gsum1,gsq1,gsum2,gsq2 (4x256 floats)
  float* gsq  = gsum + 256;
  float* gsum2 = gsum + 512;
  float* gsq2  = gsum + 768;
  bf16* wqkvt = (bf16*)p;   p += 393216;    // [768][256]
  bf16* wot   = (bf16*)p;   p += 131072;    // [256][256]
  bf16* w1t   = (bf16*)p;   p += 524288;    // [1024][256]
  bf16* w2t   = (bf16*)p;   p += 524288;    // [256][1024]
  float* out  = (float*)d_out;         // FP32 output: x_mid, then final (in place)
  const int* F14 = flags + 14;         // const bf16 flag (0)

  // ---- dtype probes + stat-buffer zero (one memset covers all 4 stat vectors) ----
  hipMemsetAsync(flags, 0, 256, stream);
  hipMemsetAsync(gsum, 0, 1024 * sizeof(float), stream);
  PtrPack pk;
  for (int i = 0; i < 14; i++) { pk.p[i] = d_in[i]; pk.n[i] = in_sizes[i]; }
  probe_all_k<<<14, 64, 0, stream>>>(pk, flags);

  // ---- one-time weight transpose to bf16 [N][K] (one launch) ----
  wconv_all_k<<<3072, 256, 0, stream>>>(Wqkv, Wo, W1, W2, flags,
                                        wqkvt, wot, w1t, w2t);

  // ---- block 1: BN1 + LIF -> s1 bits ----
  bnstats_k<<<256, 1024, 0, stream>>>(x_in, flags + 0, gsum, gsq);
  lif_k<<<MT / 512, 256, 0, stream>>>(x_in, flags + 0, gsum, gsq,
                                      d_in[1], flags + 1, d_in[2], flags + 2, bits);

  // ---- region routing (fp32: exact top-k indices) ----
  regmean_k<<<512, 256, 0, stream>>>(bits, sreg);
  pgemm_k<<<dim3(8, 8), 256, 0, stream>>>(sreg, Wqkv, flags + 3, bqkv, flags + 4, qkr);
  afftopk_k<<<512, 256, 0, stream>>>(qkr, idxb);

  // ---- attention chunks: qkv -> attn -> x_mid = x + scl*(ctx@Wo+bo), BN2 stats fused ----
  for (int gb = 0; gb < 32; gb += C) {
    size_t tok0 = (size_t)gb * 1024;
    dgemm_k<3, 1><<<dim3(6, C * 8), 256, 0, stream>>>(
        (const void*)((const u32*)bits + tok0 * 8), wqkvt,
        bqkv, flags + 4, qkvb, nullptr, F14, nullptr, F14, 768, 256, 0,
        nullptr, nullptr);
    attn_k<<<C * 128, 256, 0, stream>>>(qkvb, idxb + gb * 64, ctxb);
    dgemm_k<5, 0><<<dim3(2, C * 8), 256, 0, stream>>>(
        ctxb, wot, bo, flags + 6, out, x_in, flags + 0,
        scale, flags + 13, 256, 256, tok0 * 256, gsum2, gsq2);
  }

  // ---- block 2: LIF on x_mid (stats came from the fused Wo epilogue) ----
  lif_k<<<MT / 512, 256, 0, stream>>>(out, flags + 15, gsum2, gsq2,
                                      d_in[7], flags + 7, d_in[8], flags + 8, bits);

  // ---- fused FFN v4 (measured best): one launch over all 32768 tokens ----
  ffn_k<<<NTOK / 64, 512, 0, stream>>>(bits, w1t, b1, flags + 10,
                                       w2t, b2, flags + 12,
                                       out, scale, flags + 13);
}

// Round 15
// 397.449 us; speedup vs baseline: 1.0287x; 1.0287x over previous
//
#include <hip/hip_runtime.h>
#include <hip/hip_bf16.h>
#include <math.h>

typedef __hip_bfloat16 bf16;
typedef unsigned long long u64;
typedef unsigned int u32;

#define LTT 4
#define DIM 256
#define NTOK 32768      // total tokens (4*8*1024)
#define MT 2097152      // elements per time step (8192 tokens * 256)
#define NTOT 8388608

typedef __attribute__((ext_vector_type(8))) short short8;   // 8 bf16 (4 VGPRs)
typedef __attribute__((ext_vector_type(4))) float f32x4;
typedef __attribute__((ext_vector_type(4))) u32 u32x4;

// dual-dtype load with finite clamp: f=1 -> fp32, f=0 -> bf16
__device__ __forceinline__ float ldin(const void* p, size_t i, int f) {
  float v = f ? ((const float*)p)[i] : __bfloat162float(((const bf16*)p)[i]);
  return isfinite(v) ? v : 0.0f;
}

__device__ __forceinline__ short bf16bits(float x) {
  union { bf16 b; short s; } u; u.b = __float2bfloat16(x); return u.s;
}

// ---------------- per-input dtype probes, all inputs in one launch ----------------
struct PtrPack { const void* p[14]; int n[14]; };

__global__ void probe_all_k(PtrPack pk, int* flags) {
  int b = blockIdx.x;            // 14 blocks, one per input
  int tid = threadIdx.x;         // 64
  const unsigned short* u = (const unsigned short*)pk.p[b];
  int nelem = pk.n[b];
  int n = nelem < 1024 ? nelem : 1024;
  bool big = false, nz = false;
  for (int i = tid; i < n; i += 64) {
    unsigned short h = u[i];
    if (((h >> 7) & 0xFF) >= 0xC0) big = true;
    if (h != 0) nz = true;
  }
  u64 bm = __ballot(big);
  u64 zm = __ballot(nz);
  if (tid == 0) {
    unsigned short h0 = u[0];
    int f = 0;
    if (bm != 0ull) f = 1;
    else if (h0 == 0 && (zm != 0ull || n == 1)) f = 1;
    flags[b] = f;
    if (b == 0) flags[15] = 1;   // const fp32 flag
  }
}

// ---------------- batchnorm stats (BN1 only; BN2 fused into Wo epilogue) ----------
__global__ void __launch_bounds__(1024)
bnstats_k(const void* __restrict__ x, const int* __restrict__ fxp,
          float* __restrict__ gsum, float* __restrict__ gsq) {
  int fx = *fxp;
  int c = threadIdx.x & 255;            // channel
  int part = threadIdx.x >> 8;          // 0..3
  int tok0 = blockIdx.x * 128 + part * 32;
  float s = 0.f, q = 0.f;
  for (int t = 0; t < 32; t++) {
    float v = ldin(x, (size_t)(tok0 + t) * DIM + c, fx);
    s += v; q += v * v;
  }
  __shared__ float ls[4][256], lq[4][256];
  ls[part][c] = s; lq[part][c] = q;
  __syncthreads();
  if (threadIdx.x < 256) {
    float S = ls[0][c] + ls[1][c] + ls[2][c] + ls[3][c];
    float Q = lq[0][c] + lq[1][c] + lq[2][c] + lq[3][c];
    atomicAdd(&gsum[c], S);
    atomicAdd(&gsq[c], Q);
  }
}

// ---------------- fused BN-apply + LIF scan over t; spikes bit-packed ----------------
// All 4 time-step loads hoisted ahead of the serial scan (independent addresses).
__global__ void lif_k(const void* __restrict__ x, const int* __restrict__ fxp,
                      const float* __restrict__ gsum, const float* __restrict__ gsq,
                      const void* __restrict__ gamma, const int* __restrict__ fgp,
                      const void* __restrict__ beta, const int* __restrict__ fbp,
                      u64* __restrict__ bits) {
  int fx = *fxp, fg = *fgp, fb = *fbp;
  int m = blockIdx.x * 256 + threadIdx.x;   // [0, MT)
  int c = m & (DIM - 1);
  int lane = threadIdx.x & 63;
  float mean = gsum[c] * (1.0f / 32768.0f);
  float var  = gsq[c] * (1.0f / 32768.0f) - mean * mean;
  float inv  = rsqrtf(var + 1e-5f);
  float g = ldin(gamma, c, fg), be = ldin(beta, c, fb);
  float xn[LTT];
  #pragma unroll
  for (int t = 0; t < LTT; t++)
    xn[t] = (ldin(x, (size_t)t * MT + m, fx) - mean) * inv * g + be;
  float v = 0.f;
  #pragma unroll
  for (int t = 0; t < LTT; t++) {
    v = v + (xn[t] - v) * 0.5f;              // TAU = 2
    bool sp = (v - 1.0f >= 0.0f);            // VTH = 1
    u64 bl = __ballot(sp);
    if (lane == 0) bits[((size_t)t * MT + m) >> 6] = bl;  // wave-uniform
    v = sp ? 0.0f : v;
  }
}

__device__ __forceinline__ float gelu_f(float x) {
  return 0.5f * x * (1.0f + erff(x * 0.70710678118654752440f));
}

// ---------------- one-time weight convert+transpose (all 4 weights, one launch) ----
__global__ void wconv_all_k(const void* __restrict__ Wqkv, const void* __restrict__ Wo,
                            const void* __restrict__ W1, const void* __restrict__ W2,
                            const int* __restrict__ flags,
                            bf16* __restrict__ wqkvt, bf16* __restrict__ wot,
                            bf16* __restrict__ w1t, bf16* __restrict__ w2t) {
  int b = blockIdx.x, t = threadIdx.x;
  const void* W; const int* f; bf16* o; int K, N, n, kblk = 0;
  if (b < 768)       { W = Wqkv; f = flags + 3;  o = wqkvt; K = 256;  N = 768;  n = b; }
  else if (b < 1024) { W = Wo;   f = flags + 5;  o = wot;   K = 256;  N = 256;  n = b - 768; }
  else if (b < 2048) { W = W1;   f = flags + 9;  o = w1t;   K = 256;  N = 1024; n = b - 1024; }
  else { W = W2; f = flags + 11; o = w2t; K = 1024; N = 256;
         int q = b - 2048; kblk = q >> 8; n = q & 255; }
  int k = kblk * 256 + t;
  o[(size_t)n * K + k] = __float2bfloat16(ldin(W, (size_t)k * N + n, *f));
}

// ---------------- LDS-free direct MFMA GEMM, 128x128 tile, 4 waves ----------------
// MODE 3: O(bf16) = acc+bias    (qkv spike GEMM)
// MODE 4: Of32 = xin + scl*(acc+bias)
// MODE 5: MODE 4 + fused per-channel BN stats (Sum, SumSq) -> gs2/gq2
template <int MODE, int ABITS>
__global__ void __launch_bounds__(256)
dgemm_k(const void* __restrict__ Av, const bf16* __restrict__ Bt,
        const void* __restrict__ biasv, const int* __restrict__ fbp,
        void* O, const void* xinv, const int* __restrict__ fxp,
        const void* __restrict__ scalev, const int* __restrict__ fsp,
        int N, int K, size_t obase,
        float* __restrict__ gs2, float* __restrict__ gq2) {
  int tid = threadIdx.x;
  int lane = tid & 63, w = tid >> 6;
  int wr = w >> 1, wc = w & 1;          // wave -> 64x64 quadrant
  int kq = lane >> 4, lr = lane & 15;
  int bm = blockIdx.y * 128, bn = blockIdx.x * 128;
  f32x4 acc[4][4] = {};
  __shared__ float lsum[128], lsq[128];
  if constexpr (MODE == 5) {
    if (tid < 128) { lsum[tid] = 0.f; lsq[tid] = 0.f; }
    __syncthreads();
  }

  if constexpr (ABITS) {
    // K = 256 fixed for spike GEMMs.
    __shared__ __align__(16) short lut[256][8];
    {
      short8 e;
      #pragma unroll
      for (int j = 0; j < 8; j++) e[j] = ((tid >> j) & 1) ? (short)0x3F80 : (short)0;
      *(short8*)&lut[tid][0] = e;
    }
    const u32* Abits = (const u32*)Av;
    u32 ab[4][8];
    #pragma unroll
    for (int i = 0; i < 4; i++) {
      const u32* rp = &Abits[(size_t)(bm + wr * 64 + i * 16 + lr) * 8];
      *(u32x4*)&ab[i][0] = *(const u32x4*)&rp[0];
      *(u32x4*)&ab[i][4] = *(const u32x4*)&rp[4];
    }
    __syncthreads();
    #pragma unroll
    for (int s = 0; s < 8; s++) {        // k0 = s*32
      short8 af[4], bf[4];
      #pragma unroll
      for (int i = 0; i < 4; i++) {
        u32 byte = (ab[i][s] >> (kq * 8)) & 0xFFu;
        af[i] = *(const short8*)&lut[byte][0];
      }
      #pragma unroll
      for (int j = 0; j < 4; j++)
        bf[j] = *(const short8*)&Bt[(size_t)(bn + wc * 64 + j * 16 + lr) * 256 + s * 32 + kq * 8];
      #pragma unroll
      for (int i = 0; i < 4; i++)
        #pragma unroll
        for (int j = 0; j < 4; j++)
          acc[i][j] = __builtin_amdgcn_mfma_f32_16x16x32_bf16(af[i], bf[j], acc[i][j], 0, 0, 0);
    }
  } else {
    const bf16* Ab = (const bf16*)Av;
    for (int k0 = 0; k0 < K; k0 += 32) {
      short8 af[4], bf[4];
      #pragma unroll
      for (int i = 0; i < 4; i++)
        af[i] = *(const short8*)&Ab[(size_t)(bm + wr * 64 + i * 16 + lr) * K + k0 + kq * 8];
      #pragma unroll
      for (int j = 0; j < 4; j++)
        bf[j] = *(const short8*)&Bt[(size_t)(bn + wc * 64 + j * 16 + lr) * K + k0 + kq * 8];
      #pragma unroll
      for (int i = 0; i < 4; i++)
        #pragma unroll
        for (int j = 0; j < 4; j++)
          acc[i][j] = __builtin_amdgcn_mfma_f32_16x16x32_bf16(af[i], bf[j], acc[i][j], 0, 0, 0);
    }
  }

  // epilogue: D layout col=lane&15, row=(lane>>4)*4+r (verified mapping)
  float scl = 0.f;
  int fx = 0, fbias = *fbp;
  if (MODE >= 4) { scl = ldin(scalev, 0, *fsp); fx = *fxp; }
  int row0 = bm + wr * 64 + kq * 4;
  int col0 = bn + wc * 64 + lr;
  #pragma unroll
  for (int j = 0; j < 4; j++) {
    int n = col0 + j * 16;
    float bb = ldin(biasv, n, fbias);
    float sj = 0.f, qj = 0.f;
    #pragma unroll
    for (int i = 0; i < 4; i++) {
      #pragma unroll
      for (int r = 0; r < 4; r++) {
        int m = row0 + i * 16 + r;
        float v = acc[i][j][r] + bb;
        size_t o = obase + (size_t)m * N + n;
        if (MODE == 3) {
          ((bf16*)O)[o] = __float2bfloat16(v);
        } else {  // MODE 4/5: fp32 RMW; same element same thread
          float basev = ldin(xinv, o, fx);
          float ov = basev + scl * v;
          ((float*)O)[o] = ov;
          sj += ov; qj += ov * ov;
        }
      }
    }
    if constexpr (MODE == 5) {
      int li = wc * 64 + j * 16 + lr;
      atomicAdd(&lsum[li], sj);
      atomicAdd(&lsq[li], qj);
    }
  }
  if constexpr (MODE == 5) {
    __syncthreads();
    if (tid < 128) {
      atomicAdd(&gs2[bn + tid], lsum[tid]);
      atomicAdd(&gq2[bn + tid], lsq[tid]);
    }
  }
}

// ---------------- fused FFN v4 (best measured of session: 78-86 µs band) ---------
// out += scl*(gelu(spikes@W1+b1)@W2+b2), 512 blocks x 64 tokens x 8 waves.
// LDS = lut 4K + As 32K + hl-dbuf 32K = 68 KB. Per 128-hidden chunk: phase A
// (MFMA from As+w1t) -> gelu store hl[c&1] -> preload W2 frags -> ONE barrier ->
// phase B (MFMA into persistent acc2). Double-buffered hl: waves are bounded by
// one barrier of skew, so a write to hl[(c+1)&1] cannot race a read of hl[c&1].
// Measured-dead-ends (do not re-add): W1 reg preload (R10, +8µs via VGPR pressure);
// 2-barrier single hl (R7, +9µs); 1024x32 grid (R8, +45µs weight-stream doubling);
// setprio around MFMA (R13, null); erf_fast (R12, null - VALU not critical path).
__global__ void __launch_bounds__(512)
ffn_k(const u64* __restrict__ bits_, const bf16* __restrict__ w1t,
      const void* __restrict__ b1v, const int* __restrict__ f1p,
      const bf16* __restrict__ w2t,
      const void* __restrict__ b2v, const int* __restrict__ f2p,
      float* out, const void* __restrict__ scalev, const int* __restrict__ fsp) {
  __shared__ __align__(16) short lut[256][8];       // 4 KB byte->8xbf16
  __shared__ __align__(16) short As[32][64][8];     // 32 KB expanded spikes [kb][row]
  __shared__ __align__(16) short hl[2][16][64][8];  // 32 KB h chunk dbuf, kb-major
  int tid = threadIdx.x;            // 512
  int lane = tid & 63, w = tid >> 6;   // 8 waves
  int kq = lane >> 4, lr = lane & 15;
  int m0 = blockIdx.x * 64;
  if (tid < 256) {
    short8 e;
    #pragma unroll
    for (int j = 0; j < 8; j++) e[j] = ((tid >> j) & 1) ? (short)0x3F80 : (short)0;
    *(short8*)&lut[tid][0] = e;
  }
  __syncthreads();
  // ---- expand spikes once: thread t -> row t>>3, u32 word t&7 (kb = 4*(t&7)..+3)
  {
    int row = tid >> 3, word = tid & 7;
    u32 val = ((const u32*)bits_)[(size_t)(m0 + row) * 8 + word];
    #pragma unroll
    for (int q = 0; q < 4; q++) {
      u32 byte = (val >> (q * 8)) & 0xFFu;
      *(short8*)&As[word * 4 + q][row][0] = *(const short8*)&lut[byte][0];
    }
  }
  int f1 = *f1p;
  f32x4 acc2[4][2] = {};
  __syncthreads();

  for (int c = 0; c < 8; c++) {
    // ---- phase A: wave w -> hidden cols c*128 + w*16 .. +15
    f32x4 accA[4] = {};
    #pragma unroll
    for (int s = 0; s < 8; s++) {
      short8 bfw = *(const short8*)&w1t[(size_t)(c * 128 + w * 16 + lr) * 256 + s * 32 + kq * 8];
      #pragma unroll
      for (int i = 0; i < 4; i++) {
        short8 af = *(const short8*)&As[s * 4 + kq][i * 16 + lr][0];
        accA[i] = __builtin_amdgcn_mfma_f32_16x16x32_bf16(af, bfw, accA[i], 0, 0, 0);
      }
    }
    // gelu + bf16 -> hl[c&1][cl>>3][row][cl&7]
    {
      int cl = w * 16 + lr;
      float bb = ldin(b1v, c * 128 + cl, f1);
      #pragma unroll
      for (int i = 0; i < 4; i++)
        #pragma unroll
        for (int r = 0; r < 4; r++)
          hl[c & 1][cl >> 3][i * 16 + kq * 4 + r][cl & 7] = bf16bits(gelu_f(accA[i][r] + bb));
    }
    // preload W2 fragments for phase B (hides L2 latency under the barrier)
    short8 pb[4][2];
    #pragma unroll
    for (int ks = 0; ks < 4; ks++) {
      pb[ks][0] = *(const short8*)&w2t[(size_t)(w * 32 + lr) * 1024 + c * 128 + ks * 32 + kq * 8];
      pb[ks][1] = *(const short8*)&w2t[(size_t)(w * 32 + 16 + lr) * 1024 + c * 128 + ks * 32 + kq * 8];
    }
    __syncthreads();
    // ---- phase B: wave w -> out cols w*32 .. +31
    #pragma unroll
    for (int ks = 0; ks < 4; ks++) {
      #pragma unroll
      for (int i = 0; i < 4; i++) {
        short8 af = *(const short8*)&hl[c & 1][ks * 4 + kq][i * 16 + lr][0];
        acc2[i][0] = __builtin_amdgcn_mfma_f32_16x16x32_bf16(af, pb[ks][0], acc2[i][0], 0, 0, 0);
        acc2[i][1] = __builtin_amdgcn_mfma_f32_16x16x32_bf16(af, pb[ks][1], acc2[i][1], 0, 0, 0);
      }
    }
  }

  float scl = ldin(scalev, 0, *fsp);
  int f2 = *f2p;
  #pragma unroll
  for (int j = 0; j < 2; j++) {
    int n = w * 32 + j * 16 + lr;
    float bb = ldin(b2v, n, f2);
    #pragma unroll
    for (int i = 0; i < 4; i++)
      #pragma unroll
      for (int r = 0; r < 4; r++) {
        int row = m0 + i * 16 + kq * 4 + r;
        size_t o = (size_t)row * 256 + n;
        out[o] = out[o] + scl * (acc2[i][j][r] + bb);  // same-thread read-then-write
      }
  }
}

// ---------------- region-mean of spike bits: sreg[512][256] fp32 ----------------
__global__ void regmean_k(const u64* __restrict__ bits, float* __restrict__ sreg) {
  int blk = blockIdx.x;   // 512 regions
  int c = threadIdx.x;    // 256
  float s = 0.f;
  for (int i = 0; i < 64; i++) {
    u64 w = bits[(size_t)(blk * 64 + i) * 4 + (c >> 6)];
    s += (float)((w >> (c & 63)) & 1ull);
  }
  sreg[(size_t)blk * 256 + c] = s * (1.0f / 64.0f);
}

// ---------------- routing projection: qkr[512][512] = sreg @ Wqkv[:, :512] + bqkv ----
__global__ void __launch_bounds__(256)
pgemm_k(const float* __restrict__ A,          // sreg [512][256]
        const void* __restrict__ Bv, const int* __restrict__ fBp,   // Wqkv, row stride 768
        const void* __restrict__ biasv, const int* __restrict__ fbp,
        float* __restrict__ Oq) {             // qkr [512][512]
  int fB = *fBp, fb = *fbp;
  __shared__ float Ast[16][68];
  __shared__ float Bs[16][68];
  int tid = threadIdx.x;
  int bm = blockIdx.y * 64, bn = blockIdx.x * 64;
  int tr = tid >> 4, tc = tid & 15;
  float acc[4][4] = {};
  for (int k0 = 0; k0 < 256; k0 += 16) {
    for (int t = tid; t < 1024; t += 256) {
      int m = t >> 4, k = t & 15;
      Ast[k][m] = A[(size_t)(bm + m) * 256 + k0 + k];
    }
    for (int t = tid; t < 1024; t += 256) {
      int k = t >> 6, n = t & 63;
      Bs[k][n] = ldin(Bv, (size_t)(k0 + k) * 768 + bn + n, fB);
    }
    __syncthreads();
    #pragma unroll
    for (int kk = 0; kk < 16; kk++) {
      float4 a4 = *(const float4*)&Ast[kk][tr * 4];
      float4 b4 = *(const float4*)&Bs[kk][tc * 4];
      float a[4] = {a4.x, a4.y, a4.z, a4.w};
      float b[4] = {b4.x, b4.y, b4.z, b4.w};
      #pragma unroll
      for (int i = 0; i < 4; i++)
        #pragma unroll
        for (int jj = 0; jj < 4; jj++)
          acc[i][jj] += a[i] * b[jj];
    }
    __syncthreads();
  }
  #pragma unroll
  for (int i = 0; i < 4; i++)
    #pragma unroll
    for (int jj = 0; jj < 4; jj++) {
      int n = bn + tc * 4 + jj;
      Oq[(size_t)(bm + tr * 4 + i) * 512 + n] = acc[i][jj] + ldin(biasv, n, fb);
    }
}

// ---------------- affinity + top-4 (ties -> lowest index, matches lax.top_k) ----------------
__global__ void afftopk_k(const float* __restrict__ qkr, int* __restrict__ idx) {
  int blk = blockIdx.x;       // (t*8+b)*16 + r
  int tb = blk >> 4;
  int tid = threadIdx.x;      // 256
  int s_ = tid >> 4, p = tid & 15;
  __shared__ float part[256];
  __shared__ float aff[16];
  const float* qrow = qkr + (size_t)blk * 512;                 // q half
  const float* krow = qkr + (size_t)(tb * 16 + s_) * 512 + 256; // k half
  float acc = 0.f;
  for (int c = p * 16; c < p * 16 + 16; c++) acc += qrow[c] * krow[c];
  part[tid] = acc;
  __syncthreads();
  if (tid < 16) {
    float a = 0.f;
    for (int pp = 0; pp < 16; pp++) a += part[tid * 16 + pp];
    aff[tid] = a;
  }
  __syncthreads();
  if (tid == 0) {
    bool taken[16] = {};
    for (int kk = 0; kk < 4; kk++) {
      float best = -INFINITY; int bi = 0;
      for (int i = 0; i < 16; i++)
        if (!taken[i] && aff[i] > best) { best = aff[i]; bi = i; }
      taken[bi] = true;
      idx[blk * 4 + kk] = bi;
    }
  }
}

// ---------------- MFMA gathered attention per (b_local, r, h) ----------------
// 48 KB LDS (3 blocks/CU): Ks region is dead after QK^T, so Ps for waves 2,3
// overlay it (extra barrier between last QK^T read and first P store).
__global__ void __launch_bounds__(256)
attn_k(const bf16* __restrict__ qkv, const int* __restrict__ idx,
       bf16* __restrict__ ctx) {
  __shared__ __align__(16) short KP[8192];        // 16 KB: Ks[256][32] -> Ps waves 2,3
  __shared__ __align__(16) short Vs[32][256];     // 16 KB (rotated V^T)
  __shared__ __align__(16) short P01[8192];       // 16 KB: Ps waves 0,1
  int blk = blockIdx.x;             // (b_local*16+r)*8 + h
  int h = blk & 7, br = blk >> 3;
  int b = br >> 4;                  // chunk-local batch
  int tid = threadIdx.x;
  int base = br * 64;               // chunk-local token base
  int r0 = idx[br * 4 + 0], r1 = idx[br * 4 + 1];
  int r2 = idx[br * 4 + 2], r3 = idx[br * 4 + 3];

  #pragma unroll
  for (int c = 0; c < 4; c++) {
    int g = c * 256 + tid;
    int tk = g >> 2, ch = g & 3;
    int rs = tk >> 6;
    int rid = (rs & 2) ? ((rs & 1) ? r3 : r2) : ((rs & 1) ? r1 : r0);
    int gt = b * 1024 + rid * 64 + (tk & 63);
    short8 v = *(const short8*)&qkv[(size_t)gt * 768 + 256 + h * 32 + ch * 8];
    *(short8*)&KP[tk * 32 + ch * 8] = v;
  }
  {
    int tk = tid;
    int rs = tk >> 6;
    int rid = (rs & 2) ? ((rs & 1) ? r3 : r2) : ((rs & 1) ? r1 : r0);
    int gt = b * 1024 + rid * 64 + (tk & 63);
    const bf16* vp = &qkv[(size_t)gt * 768 + 512 + h * 32];
    short vv[32];
    *(short8*)&vv[0]  = *(const short8*)&vp[0];
    *(short8*)&vv[8]  = *(const short8*)&vp[8];
    *(short8*)&vv[16] = *(const short8*)&vp[16];
    *(short8*)&vv[24] = *(const short8*)&vp[24];
    #pragma unroll
    for (int d = 0; d < 32; d++)
      Vs[d][(tk + 8 * d) & 255] = vv[d];
  }
  __syncthreads();

  int w = tid >> 6, lane = tid & 63, kq = lane >> 4, lr = lane & 15;

  short8 qf = *(const short8*)&qkv[(size_t)(base + w * 16 + lr) * 768 + h * 32 + kq * 8];

  f32x4 s[16];
  #pragma unroll
  for (int nt = 0; nt < 16; nt++) {
    short8 kf = *(const short8*)&KP[(nt * 16 + lr) * 32 + kq * 8];
    f32x4 z = {0.f, 0.f, 0.f, 0.f};
    s[nt] = __builtin_amdgcn_mfma_f32_16x16x32_bf16(qf, kf, z, 0, 0, 0);
  }

  const float cs = 0.17677669529663687f;   // 1/sqrt(32)
  float mx[4] = {-INFINITY, -INFINITY, -INFINITY, -INFINITY};
  #pragma unroll
  for (int nt = 0; nt < 16; nt++)
    #pragma unroll
    for (int r = 0; r < 4; r++) mx[r] = fmaxf(mx[r], s[nt][r]);
  #pragma unroll
  for (int m = 1; m < 16; m <<= 1)
    #pragma unroll
    for (int r = 0; r < 4; r++) mx[r] = fmaxf(mx[r], __shfl_xor(mx[r], m, 64));
  float sum[4] = {0.f, 0.f, 0.f, 0.f};
  #pragma unroll
  for (int nt = 0; nt < 16; nt++)
    #pragma unroll
    for (int r = 0; r < 4; r++) {
      float e = __expf((s[nt][r] - mx[r]) * cs);
      s[nt][r] = e; sum[r] += e;
    }
  #pragma unroll
  for (int m = 1; m < 16; m <<= 1)
    #pragma unroll
    for (int r = 0; r < 4; r++) sum[r] += __shfl_xor(sum[r], m, 64);
  float inv[4];
  #pragma unroll
  for (int r = 0; r < 4; r++) inv[r] = 1.0f / sum[r];

  __syncthreads();   // all waves done reading Ks (KP) before Ps overlays it

  short* Pw = (w < 2) ? &P01[w * 4096] : &KP[(w - 2) * 4096];
  #pragma unroll
  for (int nt = 0; nt < 16; nt++)
    #pragma unroll
    for (int r = 0; r < 4; r++) {
      int row = kq * 4 + r;
      int col = nt * 16 + lr;
      Pw[row * 256 + (col ^ ((row & 7) << 3))] = bf16bits(s[nt][r] * inv[r]);
    }
  __syncthreads();

  f32x4 o0 = {0.f, 0.f, 0.f, 0.f}, o1 = {0.f, 0.f, 0.f, 0.f};
  #pragma unroll
  for (int kc = 0; kc < 8; kc++) {
    short8 pf = *(const short8*)
        &Pw[lr * 256 + (kc ^ ((lr >> 2) & 1)) * 32 + (kq ^ (lr & 3)) * 8];
    int d0 = lr, d1 = 16 + lr;
    short8 vf0 = *(const short8*)&Vs[d0][(kc * 32 + kq * 8 + 8 * d0) & 255];
    short8 vf1 = *(const short8*)&Vs[d1][(kc * 32 + kq * 8 + 8 * d1) & 255];
    o0 = __builtin_amdgcn_mfma_f32_16x16x32_bf16(pf, vf0, o0, 0, 0, 0);
    o1 = __builtin_amdgcn_mfma_f32_16x16x32_bf16(pf, vf1, o1, 0, 0, 0);
  }

  #pragma unroll
  for (int r = 0; r < 4; r++) {
    int q = base + w * 16 + kq * 4 + r;
    ctx[(size_t)q * 256 + h * 32 + lr]      = __float2bfloat16(o0[r]);
    ctx[(size_t)q * 256 + h * 32 + 16 + lr] = __float2bfloat16(o1[r]);
  }
}

// ---------------- launch ----------------
extern "C" void kernel_launch(void* const* d_in, const int* in_sizes, int n_in,
                              void* d_out, int out_size, void* d_ws, size_t ws_size,
                              hipStream_t stream) {
  const void* x_in = d_in[0];
  const void* Wqkv = d_in[3];
  const void* bqkv = d_in[4];
  const void* Wo   = d_in[5];
  const void* bo   = d_in[6];
  const void* W1   = d_in[9];
  const void* b1   = d_in[10];
  const void* W2   = d_in[11];
  const void* b2   = d_in[12];
  const void* scale = d_in[13];

  const size_t MISC = 256 + 1048576 + 524288 + 8192 + 1048576 + 4096
                    + 393216 + 131072 + 524288 + 524288;
  int C;  // batches (of 1024 tokens) per attention chunk; 32 = whole tensor
  if      (MISC + (size_t)32 * 2097152 <= ws_size) C = 32;   // ~68.2 MB
  else if (MISC + (size_t)16 * 2097152 <= ws_size) C = 16;   // ~37.7 MB
  else if (MISC + (size_t)8  * 2097152 <= ws_size) C = 8;    // ~20.9 MB
  else if (MISC + (size_t)4  * 2097152 <= ws_size) C = 4;    // ~12.5 MB
  else                                             C = 1;
  size_t r0 = (size_t)C * 2097152;   // qkvb (C*1.5MB) + ctxb (C*0.5MB)

  char* ws = (char*)d_ws;
  int*  flags = (int*)ws;      // [0..13] per-input dtype; [14]=0 (bf16); [15]=1 (fp32)
  char* p = ws + 256;
  bf16* qkvb = (bf16*)p;
  bf16* ctxb = (bf16*)(p + (size_t)C * 1572864);
  p += r0;
  float* qkr  = (float*)p;  p += 1048576;   // [512][512] (q||k routing projections)
  float* sreg = (float*)p;  p += 524288;    // [512][256] region means
  int*   idxb = (int*)p;    p += 8192;
  u64*   bits = (u64*)p;    p += 1048576;   // s1 bits, later s2 bits
  float* gsum = (float*)p;  p += 4096;      // gsum1,gsq1,gsum2,gsq2 (4x256 floats)
  float* gsq  = gsum + 256;
  float* gsum2 = gsum + 512;
  float* gsq2  = gsum + 768;
  bf16* wqkvt = (bf16*)p;   p += 393216;    // [768][256]
  bf16* wot   = (bf16*)p;   p += 131072;    // [256][256]
  bf16* w1t   = (bf16*)p;   p += 524288;    // [1024][256]
  bf16* w2t   = (bf16*)p;   p += 524288;    // [256][1024]
  float* out  = (float*)d_out;         // FP32 output: x_mid, then final (in place)
  const int* F14 = flags + 14;         // const bf16 flag (0)

  // ---- dtype probes + stat-buffer zero (one memset covers all 4 stat vectors) ----
  hipMemsetAsync(flags, 0, 256, stream);
  hipMemsetAsync(gsum, 0, 1024 * sizeof(float), stream);
  PtrPack pk;
  for (int i = 0; i < 14; i++) { pk.p[i] = d_in[i]; pk.n[i] = in_sizes[i]; }
  probe_all_k<<<14, 64, 0, stream>>>(pk, flags);

  // ---- one-time weight transpose to bf16 [N][K] (one launch) ----
  wconv_all_k<<<3072, 256, 0, stream>>>(Wqkv, Wo, W1, W2, flags,
                                        wqkvt, wot, w1t, w2t);

  // ---- block 1: BN1 + LIF -> s1 bits ----
  bnstats_k<<<256, 1024, 0, stream>>>(x_in, flags + 0, gsum, gsq);
  lif_k<<<MT / 256, 256, 0, stream>>>(x_in, flags + 0, gsum, gsq,
                                      d_in[1], flags + 1, d_in[2], flags + 2, bits);

  // ---- region routing (fp32: exact top-k indices) ----
  regmean_k<<<512, 256, 0, stream>>>(bits, sreg);
  pgemm_k<<<dim3(8, 8), 256, 0, stream>>>(sreg, Wqkv, flags + 3, bqkv, flags + 4, qkr);
  afftopk_k<<<512, 256, 0, stream>>>(qkr, idxb);

  // ---- attention chunks: qkv -> attn -> x_mid = x + scl*(ctx@Wo+bo), BN2 stats fused ----
  for (int gb = 0; gb < 32; gb += C) {
    size_t tok0 = (size_t)gb * 1024;
    dgemm_k<3, 1><<<dim3(6, C * 8), 256, 0, stream>>>(
        (const void*)((const u32*)bits + tok0 * 8), wqkvt,
        bqkv, flags + 4, qkvb, nullptr, F14, nullptr, F14, 768, 256, 0,
        nullptr, nullptr);
    attn_k<<<C * 128, 256, 0, stream>>>(qkvb, idxb + gb * 64, ctxb);
    dgemm_k<5, 0><<<dim3(2, C * 8), 256, 0, stream>>>(
        ctxb, wot, bo, flags + 6, out, x_in, flags + 0,
        scale, flags + 13, 256, 256, tok0 * 256, gsum2, gsq2);
  }

  // ---- block 2: LIF on x_mid (stats came from the fused Wo epilogue) ----
  lif_k<<<MT / 256, 256, 0, stream>>>(out, flags + 15, gsum2, gsq2,
                                      d_in[7], flags + 7, d_in[8], flags + 8, bits);

  // ---- fused FFN v4 (measured best): one launch over all 32768 tokens ----
  ffn_k<<<NTOK / 64, 512, 0, stream>>>(bits, w1t, b1, flags + 10,
                                       w2t, b2, flags + 12,
                                       out, scale, flags + 13);
}